// Round 7
// baseline (101.006 us; speedup 1.0000x reference)
//
#include <hip/hip_runtime.h>

// Chamfer distance, fp32 VALU, register-tiled.
// dist(p,q) = |p|^2 + |q|^2 - 2 p.q ; |p|^2 folded out of the min, |q|^2
// precomputed during LDS staging.
//
// R4: v_pk_fma_f32 + 512-thread blocks -> 48.5us dispatch (bundled change!).
// R5-R9: launch_bounds arg2 acts as min BLOCKS/CU ((512,8)->cap32,
// (512,4)->cap64, (512,2)->cap128); manual q-pipeline + dbuf = VGPR bomb.
// R10: dbuf + T14 early-issue, clean 64 VGPR: 46.36us == R7. Staging was
// already hidden. All three latency attacks (TLP, reg pipeline, stage
// overlap) returned ~0.
// R11 theory: v_pk_fma_f32 is QUARTER-rate on CDNA4 (2 FMA/lane over 4
// passes = no throughput gain over scalar, just fewer insts). Under 8cyc:
// pipe busy = 96% of 46.3us (44.4 predicted) -- we're AT the packed
// roofline, explaining every null result. Under 4cyc: busy 52% with no
// stall source found. Experiment: swap pk asm -> scalar fmaf chains (same
// structure). Predict 25-29us if quarter-rate, ~46-50 if half-rate.

#define THREADS 512
#define P 8        // src points per thread
#define S 32       // target slices per block (one 16-lane group per slice)
#define G 128      // src points per block = 16 lanes * P
#define TILE 32    // targets per slice per staging tile (double-buffered)
#define LSTRIDE (TILE + 1)  // +1 float4 pad -> disjoint banks across groups
#define TSPLIT 2   // target-dimension split across blocks
#define BUFSZ (S * LSTRIDE)

typedef float float2_t __attribute__((ext_vector_type(2)));
typedef float float4_t __attribute__((ext_vector_type(4)));

__global__ __launch_bounds__(THREADS, 2) void chamfer_min_kernel(
    const float* __restrict__ pred, const float* __restrict__ target,
    float* __restrict__ wsmin, int M) {
  const int blocksPerDir = M / G;  // 64
  int bid = blockIdx.x;
  int pblk = bid % blocksPerDir;
  int rest = bid / blocksPerDir;
  int ts = rest % TSPLIT;          // which target half
  int bd = rest / TSPLIT;
  int dir = bd & 1;
  int b = bd >> 1;
  const float* src = (dir ? target : pred) + (size_t)b * M * 3;
  const float* ref = (dir ? pred : target) + (size_t)b * M * 3;

  __shared__ float4_t lds[2 * BUFSZ];  // 33.8 KB double buffer; epilogue reuse

  int t = threadIdx.x;
  int g = t >> 4;  // slice 0..31 (uniform per 16-lane group)
  int l = t & 15;

  float ax[P], ay[P], az[P];  // -2*p, one point per entry
  int pbase = pblk * G;
#pragma unroll
  for (int i = 0; i < P; ++i) {
    int p = pbase + l + 16 * i;
    float x = src[p * 3 + 0], y = src[p * 3 + 1], z = src[p * 3 + 2];
    ax[i] = -2.f * x;
    ay[i] = -2.f * y;
    az[i] = -2.f * z;
  }
  float mn[P];
#pragma unroll
  for (int i = 0; i < P; ++i) mn[i] = 3.0e38f;

  const int spanLen = M / TSPLIT;      // 4096 targets for this block
  const int tbase = ts * spanLen;
  const int sliceLen = spanLen / S;    // 128
  const int ntiles = sliceLen / TILE;  // 4

  // Staging: each thread owns 2 consecutive entries (6 floats) per tile.
  const int sidx = 2 * t;
  const int ss = sidx >> 5;            // entry slice (TILE=32)
  const int sjj = sidx & (TILE - 1);   // jj, jj+1 stay in-slice (even)
  const int nb = tbase + ss * sliceLen + sjj;  // + k*TILE per tile
  float rx0, ry0, rz0, rx1, ry1, rz1;

  // prologue: stage tile 0
  {
    int n = nb;  // k = 0
    rx0 = ref[n * 3 + 0]; ry0 = ref[n * 3 + 1]; rz0 = ref[n * 3 + 2];
    rx1 = ref[n * 3 + 3]; ry1 = ref[n * 3 + 4]; rz1 = ref[n * 3 + 5];
    float4_t* dst = lds + ss * LSTRIDE + sjj;
    dst[0] = (float4_t){rx0, ry0, rz0, rx0 * rx0 + ry0 * ry0 + rz0 * rz0};
    dst[1] = (float4_t){rx1, ry1, rz1, rx1 * rx1 + ry1 * ry1 + rz1 * rz1};
  }
  __syncthreads();

  int cur = 0;
  for (int k = 0; k < ntiles; ++k) {
    // issue next tile's global loads before compute (land under it)
    if (k + 1 < ntiles) {
      int n = nb + (k + 1) * TILE;
      rx0 = ref[n * 3 + 0]; ry0 = ref[n * 3 + 1]; rz0 = ref[n * 3 + 2];
      rx1 = ref[n * 3 + 3]; ry1 = ref[n * 3 + 4]; rz1 = ref[n * 3 + 5];
    }
    const float4_t* tp = lds + cur * BUFSZ + g * LSTRIDE;
#pragma unroll 2
    for (int j = 0; j < TILE; j += 4) {
      float4_t q0 = tp[j + 0];  // broadcast reads, disjoint banks per wave
      float4_t q1 = tp[j + 1];
      float4_t q2 = tp[j + 2];
      float4_t q3 = tp[j + 3];
#pragma unroll
      for (int i = 0; i < P; ++i) {
        // d = ax*qx + ay*qy + az*qz + qw  (3 fmaf per pair, scalar VALU)
        float d0 = fmaf(ax[i], q0.x, fmaf(ay[i], q0.y, fmaf(az[i], q0.z, q0.w)));
        float d1 = fmaf(ax[i], q1.x, fmaf(ay[i], q1.y, fmaf(az[i], q1.z, q1.w)));
        float d2 = fmaf(ax[i], q2.x, fmaf(ay[i], q2.y, fmaf(az[i], q2.z, q2.w)));
        float d3 = fmaf(ax[i], q3.x, fmaf(ay[i], q3.y, fmaf(az[i], q3.z, q3.w)));
        mn[i] = fminf(fminf(mn[i], d0), d1);  // v_min3
        mn[i] = fminf(fminf(mn[i], d2), d3);
      }
    }
    // write staged tile into the other buffer; one barrier per tile
    if (k + 1 < ntiles) {
      float4_t* dst = lds + (cur ^ 1) * BUFSZ + ss * LSTRIDE + sjj;
      dst[0] = (float4_t){rx0, ry0, rz0, rx0 * rx0 + ry0 * ry0 + rz0 * rz0};
      dst[1] = (float4_t){rx1, ry1, rz1, rx1 * rx1 + ry1 * ry1 + rz1 * rz1};
    }
    __syncthreads();
    cur ^= 1;
  }

  // Combine the S slice-mins per point, add |p|^2 back, store per-split min.
  float* lmin = (float*)lds;  // [S][G] floats (16 KB, overlays staging)
#pragma unroll
  for (int i = 0; i < P; ++i) {
    lmin[g * G + (l + 16 * i)] = mn[i];
  }
  __syncthreads();
  if (t < G) {
    float m = 3.0e38f;
#pragma unroll
    for (int s = 0; s < S; ++s) m = fminf(m, lmin[s * G + t]);
    int p = pbase + t;
    float x = src[p * 3 + 0], y = src[p * 3 + 1], z = src[p * 3 + 2];
    int pid = (b * 2 + dir) * M + p;               // global point id
    wsmin[(size_t)pid * TSPLIT + ts] = (x * x + y * y + z * z) + m;
  }
}

// Min over the TSPLIT partials per point, then sum everything (double acc).
__global__ __launch_bounds__(256) void chamfer_reduce_kernel(
    const float* __restrict__ wsmin, float* __restrict__ out, int npts,
    float scale) {
  int tid = blockIdx.x * blockDim.x + threadIdx.x;
  int stride = gridDim.x * blockDim.x;
  double acc = 0.0;
  for (int p = tid; p < npts; p += stride) {
    float2_t v = ((const float2_t*)wsmin)[p];  // TSPLIT=2 contiguous
    acc += (double)fminf(v.x, v.y);
  }
  for (int off = 32; off > 0; off >>= 1) acc += __shfl_down(acc, off, 64);
  __shared__ double wsum[256 / 64];
  int t = threadIdx.x;
  if ((t & 63) == 0) wsum[t >> 6] = acc;
  __syncthreads();
  if (t == 0) {
    double s = 0.0;
#pragma unroll
    for (int w = 0; w < 256 / 64; ++w) s += wsum[w];
    atomicAdd(out, (float)(s * (double)scale));
  }
}

extern "C" void kernel_launch(void* const* d_in, const int* in_sizes, int n_in,
                              void* d_out, int out_size, void* d_ws,
                              size_t ws_size, hipStream_t stream) {
  const float* pred = (const float*)d_in[0];
  const float* target = (const float*)d_in[1];
  float* out = (float*)d_out;
  float* wsmin = (float*)d_ws;  // B*2*M*TSPLIT floats = 512 KB
  const int B = 4;
  const int M = in_sizes[0] / (B * 3);  // 8192

  // mean_b[ mean_m(min) + mean_n(min) ] with M==N  ->  sum_all / (B*M)
  float scale = 1.0f / (float)(B * M);

  hipMemsetAsync(out, 0, sizeof(float), stream);  // d_out is poisoned 0xAA
  int blocks = B * 2 * (M / G) * TSPLIT;          // 1024
  chamfer_min_kernel<<<blocks, THREADS, 0, stream>>>(pred, target, wsmin, M);
  int npts = B * 2 * M;                           // 65536
  chamfer_reduce_kernel<<<64, 256, 0, stream>>>(wsmin, out, npts, scale);
}